// Round 3
// baseline (597.806 us; speedup 1.0000x reference)
//
#include <hip/hip_runtime.h>
#include <math.h>

#define D_FEAT 32
#define NCAP 50048            // >= N+1 ints per array
#define GSZ 8                 // nodes per gather block
#define CAP 640               // LDS edge-stage capacity (mean 256, +24 sigma)
#define SCAN_T 1024

// ---------------- K1: per-node histogram (global atomics) ----------------
__global__ __launch_bounds__(256) void hist_kernel(const int* __restrict__ dst,
                                                   int* __restrict__ nodeCount, int E) {
    int gtid = blockIdx.x * 256 + threadIdx.x;
    int gthreads = gridDim.x * 256;
    int E4 = E >> 2;
    const int4* dst4 = (const int4*)dst;
    for (int i = gtid; i < E4; i += gthreads) {
        int4 d = dst4[i];
        atomicAdd(&nodeCount[d.x], 1);
        atomicAdd(&nodeCount[d.y], 1);
        atomicAdd(&nodeCount[d.z], 1);
        atomicAdd(&nodeCount[d.w], 1);
    }
    for (int e = (E4 << 2) + gtid; e < E; e += gthreads)
        atomicAdd(&nodeCount[dst[e]], 1);
}

// ---------------- K2: single-block scan of N+1 counts -> bases + cursors ----------------
__global__ __launch_bounds__(SCAN_T) void scan_kernel(const int* __restrict__ nodeCount,
                                                      int* __restrict__ nodeBase,
                                                      int* __restrict__ nodeCursor, int N) {
    __shared__ int lds[SCAN_T];
    int tid = threadIdx.x;
    int total = N + 1;                       // count[N] == 0, gives nodeBase[N] = E
    int chunk = (total + SCAN_T - 1) / SCAN_T;
    int lo = tid * chunk;
    int hi = lo + chunk; if (hi > total) hi = total;
    int s = 0;
    for (int i = lo; i < hi; i++) s += nodeCount[i];
    lds[tid] = s;
    __syncthreads();
    for (int off = 1; off < SCAN_T; off <<= 1) {
        int t = (tid >= off) ? lds[tid - off] : 0;
        __syncthreads();
        lds[tid] += t;
        __syncthreads();
    }
    int run = lds[tid] - s;                  // exclusive prefix of this chunk
    for (int i = lo; i < hi; i++) {
        nodeBase[i] = run;
        nodeCursor[i] = run;
        run += nodeCount[i];
    }
}

// ---------------- K3: place edge ids into node-sorted order ----------------
__global__ __launch_bounds__(256) void place_kernel(const int* __restrict__ dst,
                                                    int* __restrict__ nodeCursor,
                                                    int* __restrict__ keys, int E) {
    int gtid = blockIdx.x * 256 + threadIdx.x;
    int gthreads = gridDim.x * 256;
    int E4 = E >> 2;
    const int4* dst4 = (const int4*)dst;
    for (int i = gtid; i < E4; i += gthreads) {
        int4 d = dst4[i];
        int e = i << 2;
        int r0 = atomicAdd(&nodeCursor[d.x], 1); keys[r0] = e;
        int r1 = atomicAdd(&nodeCursor[d.y], 1); keys[r1] = e + 1;
        int r2 = atomicAdd(&nodeCursor[d.z], 1); keys[r2] = e + 2;
        int r3 = atomicAdd(&nodeCursor[d.w], 1); keys[r3] = e + 3;
    }
    for (int e = (E4 << 2) + gtid; e < E; e += gthreads) {
        int r = atomicAdd(&nodeCursor[dst[e]], 1); keys[r] = e;
    }
}

// ---------------- K4: gather + reduce + finalize ----------------
// Block = 8 nodes. Wave layout: lane = (rowslot rs 0..7) x (feature-octet fo 0..7);
// each lane loads float4 -> one wave-load covers 8 full rows (1 KB).
__global__ __launch_bounds__(256) void gather_kernel(
        const float* __restrict__ m,
        const int* __restrict__ keys,
        const int* __restrict__ nodeBase,
        const float* __restrict__ w,
        const float* __restrict__ bia,
        float* __restrict__ out, int N) {
    __shared__ int seidS[CAP];
    __shared__ int noffS[GSZ + 1];
    const int g = blockIdx.x;
    const int tid = threadIdx.x;

    if (tid < GSZ + 1) {
        int n = g * GSZ + tid;
        if (n > N) n = N;
        noffS[tid] = nodeBase[n];
    }
    __syncthreads();
    const int gs = noffS[0];
    int cnt = noffS[GSZ] - gs;
    if (cnt > CAP) cnt = CAP;          // statistically impossible; OOB guard
    for (int i = tid; i < cnt; i += 256) seidS[i] = keys[gs + i];
    __syncthreads();

    const float w0 = w[0], w1 = w[1], w2 = w[2], w3 = w[3], bb = bia[0];
    const int lane = tid & 63;
    const int wv = tid >> 6;
    const int fo = lane & 7;           // features 4*fo .. 4*fo+3
    const int rs = lane >> 3;          // row slot 0..7

    for (int nl = wv; nl < GSZ; nl += 4) {
        int node = g * GSZ + nl;
        if (node >= N) break;
        int s0 = noffS[nl] - gs;     if (s0 > cnt) s0 = cnt;
        int e0 = noffS[nl + 1] - gs; if (e0 > cnt) e0 = cnt;
        int deg = e0 - s0;
        float sa0 = 0.f, sa1 = 0.f, sa2 = 0.f, sa3 = 0.f;
        float mn0 = INFINITY, mn1 = INFINITY, mn2 = INFINITY, mn3 = INFINITY;
        float mx0 = -INFINITY, mx1 = -INFINITY, mx2 = -INFINITY, mx3 = -INFINITY;
        for (int j = s0 + rs; j < e0; j += 8) {
            int eid = seidS[j];
            const float4 v = *(const float4*)&m[eid * D_FEAT + (fo << 2)];
            sa0 += v.x; mn0 = fminf(mn0, v.x); mx0 = fmaxf(mx0, v.x);
            sa1 += v.y; mn1 = fminf(mn1, v.y); mx1 = fmaxf(mx1, v.y);
            sa2 += v.z; mn2 = fminf(mn2, v.z); mx2 = fmaxf(mx2, v.z);
            sa3 += v.w; mn3 = fminf(mn3, v.w); mx3 = fmaxf(mx3, v.w);
        }
        #pragma unroll
        for (int mask = 8; mask <= 32; mask <<= 1) {   // fold row slots, fo fixed
            sa0 += __shfl_xor(sa0, mask, 64);
            sa1 += __shfl_xor(sa1, mask, 64);
            sa2 += __shfl_xor(sa2, mask, 64);
            sa3 += __shfl_xor(sa3, mask, 64);
            mn0 = fminf(mn0, __shfl_xor(mn0, mask, 64));
            mn1 = fminf(mn1, __shfl_xor(mn1, mask, 64));
            mn2 = fminf(mn2, __shfl_xor(mn2, mask, 64));
            mn3 = fminf(mn3, __shfl_xor(mn3, mask, 64));
            mx0 = fmaxf(mx0, __shfl_xor(mx0, mask, 64));
            mx1 = fmaxf(mx1, __shfl_xor(mx1, mask, 64));
            mx2 = fmaxf(mx2, __shfl_xor(mx2, mask, 64));
            mx3 = fmaxf(mx3, __shfl_xor(mx3, mask, 64));
        }
        if (rs == 0) {
            bool has = deg > 0;
            float inv = 1.0f / fmaxf((float)deg, 1.0f);
            float4 o;
            o.x = w0 * sa0 + w1 * (has ? mn0 : 0.f) + w2 * (has ? mx0 : 0.f) + w3 * (sa0 * inv) + bb;
            o.y = w0 * sa1 + w1 * (has ? mn1 : 0.f) + w2 * (has ? mx1 : 0.f) + w3 * (sa1 * inv) + bb;
            o.z = w0 * sa2 + w1 * (has ? mn2 : 0.f) + w2 * (has ? mx2 : 0.f) + w3 * (sa2 * inv) + bb;
            o.w = w0 * sa3 + w1 * (has ? mn3 : 0.f) + w2 * (has ? mx3 : 0.f) + w3 * (sa3 * inv) + bb;
            *(float4*)&out[node * D_FEAT + (fo << 2)] = o;
        }
    }
}

extern "C" void kernel_launch(void* const* d_in, const int* in_sizes, int n_in,
                              void* d_out, int out_size, void* d_ws, size_t ws_size,
                              hipStream_t stream) {
    const float* m   = (const float*)d_in[0];
    const int*   dst = (const int*)  d_in[1];
    const float* w   = (const float*)d_in[2];
    const float* b   = (const float*)d_in[3];
    float* outp = (float*)d_out;

    int E = in_sizes[0] / D_FEAT;           // 1,600,000
    int N = out_size    / D_FEAT;           // 50,000

    int* ws = (int*)d_ws;
    int* nodeCount  = ws;                       // NCAP
    int* nodeBase   = nodeCount  + NCAP;        // NCAP (uses N+1)
    int* nodeCursor = nodeBase   + NCAP;        // NCAP
    int* keys       = nodeCursor + NCAP;        // E

    hipMemsetAsync(nodeCount, 0, NCAP * sizeof(int), stream);

    int nEdgeBlocks = (E / 4 + 255) / 256;      // 1563: one int4 per thread
    int nGather = (N + GSZ - 1) / GSZ;          // 6250

    hipLaunchKernelGGL(hist_kernel, dim3(nEdgeBlocks), dim3(256), 0, stream,
                       dst, nodeCount, E);
    hipLaunchKernelGGL(scan_kernel, dim3(1), dim3(SCAN_T), 0, stream,
                       nodeCount, nodeBase, nodeCursor, N);
    hipLaunchKernelGGL(place_kernel, dim3(nEdgeBlocks), dim3(256), 0, stream,
                       dst, nodeCursor, keys, E);
    hipLaunchKernelGGL(gather_kernel, dim3(nGather), dim3(256), 0, stream,
                       m, keys, nodeBase, w, b, outp, N);
}

// Round 4
// 335.123 us; speedup vs baseline: 1.7838x; 1.7838x over previous
//
#include <hip/hip_runtime.h>
#include <math.h>

#define D_FEAT 32
#define BSHIFT 5                 // 32 nodes per bucket
#define NODES_PER_BKT 32
#define TILE 8192
#define PT 32                    // edges per thread in hist/partition (TILE/256)
#define MAXBKT 2048              // >= 1563, pow2
#define CAP 2048                 // bucket capacity (mean 1024, +32 sigma)

// ---------------- K1: bucket histogram (int4 loads) ----------------
__global__ void hist_kernel(const int* __restrict__ dst, int* __restrict__ bucketCount,
                            int E4, int nbucket) {
    __shared__ int h[MAXBKT];
    for (int i = threadIdx.x; i < nbucket; i += 256) h[i] = 0;
    __syncthreads();
    const int4* dst4 = (const int4*)dst;
    int tbase4 = blockIdx.x * (TILE / 4);
    #pragma unroll
    for (int k = 0; k < PT / 4; k++) {
        int i4 = tbase4 + k * 256 + threadIdx.x;
        if (i4 < E4) {
            int4 d = dst4[i4];
            atomicAdd(&h[d.x >> BSHIFT], 1);
            atomicAdd(&h[d.y >> BSHIFT], 1);
            atomicAdd(&h[d.z >> BSHIFT], 1);
            atomicAdd(&h[d.w >> BSHIFT], 1);
        }
    }
    __syncthreads();
    for (int i = threadIdx.x; i < nbucket; i += 256) {
        int c = h[i];
        if (c) atomicAdd(&bucketCount[i], c);
    }
}

// ---------------- K2: scan bucket counts -> bases + cursors ----------------
__global__ void scan_kernel(const int* __restrict__ bucketCount,
                            int* __restrict__ bucketBase, int* __restrict__ bucketCursor,
                            int nbucket, int E) {
    __shared__ int lds[256];
    int tid = threadIdx.x;
    int vals[8];
    int s = 0;
    #pragma unroll
    for (int k = 0; k < 8; k++) {
        int i = tid * 8 + k;
        vals[k] = (i < nbucket) ? bucketCount[i] : 0;
        s += vals[k];
    }
    lds[tid] = s;
    __syncthreads();
    for (int off = 1; off < 256; off <<= 1) {
        int t = (tid >= off) ? lds[tid - off] : 0;
        __syncthreads();
        lds[tid] += t;
        __syncthreads();
    }
    int run = lds[tid] - s;   // exclusive prefix
    #pragma unroll
    for (int k = 0; k < 8; k++) {
        int i = tid * 8 + k;
        if (i < nbucket) { bucketBase[i] = run; bucketCursor[i] = run; }
        run += vals[k];
    }
    if (tid == 0) bucketBase[nbucket] = E;
}

// ---------------- K3: partition edges into buckets (packed keys) ----------------
// pk = (b << 18) | (localnode << 13) | rank   (b<2048, local<32, rank<8192)
// key = localnode << 26 | eid                 (eid < 2^21)
__global__ void partition_kernel(const int* __restrict__ dst,
                                 int* __restrict__ bucketCursor,
                                 unsigned int* __restrict__ keys,
                                 int E4, int nbucket) {
    __shared__ int h[MAXBKT];
    __shared__ int baseL[MAXBKT];
    int tid = threadIdx.x;
    for (int i = tid; i < nbucket; i += 256) h[i] = 0;
    __syncthreads();
    const int4* dst4 = (const int4*)dst;
    int tbase4 = blockIdx.x * (TILE / 4);
    int pk[PT];
    #pragma unroll
    for (int k = 0; k < PT / 4; k++) {
        int i4 = tbase4 + k * 256 + tid;
        if (i4 < E4) {
            int4 d = dst4[i4];
            int b0 = d.x >> BSHIFT; int r0 = atomicAdd(&h[b0], 1);
            int b1 = d.y >> BSHIFT; int r1 = atomicAdd(&h[b1], 1);
            int b2 = d.z >> BSHIFT; int r2 = atomicAdd(&h[b2], 1);
            int b3 = d.w >> BSHIFT; int r3 = atomicAdd(&h[b3], 1);
            pk[4 * k + 0] = (b0 << 18) | ((d.x & (NODES_PER_BKT - 1)) << 13) | r0;
            pk[4 * k + 1] = (b1 << 18) | ((d.y & (NODES_PER_BKT - 1)) << 13) | r1;
            pk[4 * k + 2] = (b2 << 18) | ((d.z & (NODES_PER_BKT - 1)) << 13) | r2;
            pk[4 * k + 3] = (b3 << 18) | ((d.w & (NODES_PER_BKT - 1)) << 13) | r3;
        } else {
            pk[4 * k + 0] = -1; pk[4 * k + 1] = -1;
            pk[4 * k + 2] = -1; pk[4 * k + 3] = -1;
        }
    }
    __syncthreads();
    for (int i = tid; i < nbucket; i += 256) {
        int c = h[i];
        baseL[i] = c ? atomicAdd(&bucketCursor[i], c) : 0;
    }
    __syncthreads();
    #pragma unroll
    for (int k = 0; k < PT / 4; k++) {
        int i4 = tbase4 + k * 256 + tid;
        int e = i4 * 4;
        #pragma unroll
        for (int l = 0; l < 4; l++) {
            int p = pk[4 * k + l];
            if (p >= 0) {
                int b   = p >> 18;
                int loc = (p >> 13) & (NODES_PER_BKT - 1);
                int r   = p & 8191;
                keys[baseL[b] + r] = ((unsigned)loc << 26) | (unsigned)(e + l);
            }
        }
    }
}

// ---------------- K4: LDS counting-sort + float4 group gather ----------------
// Sort prologue identical to verified round-1 kernel. Gather: one node per
// 8-lane group (32 groups = 32 nodes), lane owns float4 feature chunk fo.
// One wave load instruction covers 8 rows (1 KB); unroll 4 => 32 rows in
// flight per wave.
__global__ __launch_bounds__(256) void bucket_gather_kernel(
        const float* __restrict__ m,
        const unsigned int* __restrict__ keys,
        const int* __restrict__ bucketBase,
        const float* __restrict__ w,
        const float* __restrict__ bia,
        float* __restrict__ out, int N) {
    __shared__ unsigned int ukey[CAP];
    __shared__ int seid[CAP];
    __shared__ int nh[NODES_PER_BKT];
    __shared__ int noff[NODES_PER_BKT + 1];
    __shared__ int ncur[NODES_PER_BKT];
    int bkt = blockIdx.x;
    int tid = threadIdx.x;
    int start = bucketBase[bkt];
    int cnt = bucketBase[bkt + 1] - start;
    if (cnt > CAP) cnt = CAP;        // statistically impossible; OOB guard

    if (tid < NODES_PER_BKT) nh[tid] = 0;
    __syncthreads();
    for (int i = tid; i < cnt; i += 256) {
        unsigned int k = keys[start + i];   // single global read of keys
        ukey[i] = k;
        atomicAdd(&nh[k >> 26], 1);
    }
    __syncthreads();
    if (tid < NODES_PER_BKT) {            // lanes 0..31 of wave 0: scan
        int v = nh[tid];
        int x = v;
        #pragma unroll
        for (int off = 1; off < NODES_PER_BKT; off <<= 1) {
            int t = __shfl_up(x, off, 64);
            if (tid >= off) x += t;
        }
        noff[tid + 1] = x;
        if (tid == 0) noff[0] = 0;
        ncur[tid] = x - v;                // exclusive
    }
    __syncthreads();
    for (int i = tid; i < cnt; i += 256) {
        unsigned int k = ukey[i];
        int pos = atomicAdd(&ncur[k >> 26], 1);
        seid[pos] = (int)(k & 0x03FFFFFFu);
    }
    __syncthreads();

    // ---- gather: group g = tid>>3 owns node (bkt*32 + g); fo = tid&7 ----
    const int fo  = tid & 7;          // features 4*fo .. 4*fo+3
    const int grp = tid >> 3;         // 0..31
    const int node = (bkt << BSHIFT) + grp;
    const int s0 = noff[grp];
    const int e0 = noff[grp + 1];
    const int deg = e0 - s0;
    const float w0 = w[0], w1 = w[1], w2 = w[2], w3 = w[3], bb = bia[0];

    float sa0 = 0.f, sa1 = 0.f, sa2 = 0.f, sa3 = 0.f;
    float mn0 = INFINITY, mn1 = INFINITY, mn2 = INFINITY, mn3 = INFINITY;
    float mx0 = -INFINITY, mx1 = -INFINITY, mx2 = -INFINITY, mx3 = -INFINITY;

#define ACC(v)                                              \
    sa0 += (v).x; mn0 = fminf(mn0, (v).x); mx0 = fmaxf(mx0, (v).x); \
    sa1 += (v).y; mn1 = fminf(mn1, (v).y); mx1 = fmaxf(mx1, (v).y); \
    sa2 += (v).z; mn2 = fminf(mn2, (v).z); mx2 = fmaxf(mx2, (v).z); \
    sa3 += (v).w; mn3 = fminf(mn3, (v).w); mx3 = fmaxf(mx3, (v).w);

    int j = s0;
    for (; j + 4 <= e0; j += 4) {
        int ea = seid[j], eb = seid[j + 1], ec = seid[j + 2], ed = seid[j + 3];
        float4 va = *(const float4*)&m[ea * D_FEAT + (fo << 2)];
        float4 vb = *(const float4*)&m[eb * D_FEAT + (fo << 2)];
        float4 vc = *(const float4*)&m[ec * D_FEAT + (fo << 2)];
        float4 vd = *(const float4*)&m[ed * D_FEAT + (fo << 2)];
        ACC(va); ACC(vb); ACC(vc); ACC(vd);
    }
    for (; j < e0; j++) {
        float4 v = *(const float4*)&m[seid[j] * D_FEAT + (fo << 2)];
        ACC(v);
    }
#undef ACC

    if (node < N) {
        bool has = deg > 0;
        float inv = 1.0f / fmaxf((float)deg, 1.0f);
        float4 o;
        o.x = w0 * sa0 + w1 * (has ? mn0 : 0.f) + w2 * (has ? mx0 : 0.f) + w3 * (sa0 * inv) + bb;
        o.y = w0 * sa1 + w1 * (has ? mn1 : 0.f) + w2 * (has ? mx1 : 0.f) + w3 * (sa1 * inv) + bb;
        o.z = w0 * sa2 + w1 * (has ? mn2 : 0.f) + w2 * (has ? mx2 : 0.f) + w3 * (sa2 * inv) + bb;
        o.w = w0 * sa3 + w1 * (has ? mn3 : 0.f) + w2 * (has ? mx3 : 0.f) + w3 * (sa3 * inv) + bb;
        *(float4*)&out[node * D_FEAT + (fo << 2)] = o;
    }
}

extern "C" void kernel_launch(void* const* d_in, const int* in_sizes, int n_in,
                              void* d_out, int out_size, void* d_ws, size_t ws_size,
                              hipStream_t stream) {
    const float* m   = (const float*)d_in[0];
    const int*   dst = (const int*)  d_in[1];
    const float* w   = (const float*)d_in[2];
    const float* b   = (const float*)d_in[3];

    int E = in_sizes[0] / D_FEAT;           // 1,600,000
    int N = out_size    / D_FEAT;           // 50,000
    int E4 = E / 4;
    int nbucket = (N + NODES_PER_BKT - 1) >> BSHIFT;   // 1563

    int* ws           = (int*)d_ws;
    int* bucketCount  = ws;                             // MAXBKT
    int* bucketBase   = bucketCount + MAXBKT;           // MAXBKT+1
    int* bucketCursor = bucketBase + MAXBKT + 1;        // MAXBKT
    unsigned int* keys = (unsigned int*)(bucketCursor + MAXBKT);   // E

    int nTiles = (E + TILE - 1) / TILE;     // 196

    hipMemsetAsync(bucketCount, 0, MAXBKT * sizeof(int), stream);
    hipLaunchKernelGGL(hist_kernel, dim3(nTiles), dim3(256), 0, stream,
                       dst, bucketCount, E4, nbucket);
    hipLaunchKernelGGL(scan_kernel, dim3(1), dim3(256), 0, stream,
                       bucketCount, bucketBase, bucketCursor, nbucket, E);
    hipLaunchKernelGGL(partition_kernel, dim3(nTiles), dim3(256), 0, stream,
                       dst, bucketCursor, keys, E4, nbucket);
    hipLaunchKernelGGL(bucket_gather_kernel, dim3(nbucket), dim3(256), 0, stream,
                       m, keys, bucketBase, w, b, (float*)d_out, N);
}

// Round 5
// 329.164 us; speedup vs baseline: 1.8161x; 1.0181x over previous
//
#include <hip/hip_runtime.h>
#include <math.h>

#define D_FEAT 32
#define BSHIFT 7                 // 128 nodes per bucket
#define NODES_PER_BKT 128
#define TILE 8192
#define PT 32                    // edges per thread in hist/partition (TILE/256)
#define MAXBKT 512               // >= 391, pow2
#define CAPG 5120                // gather stage capacity (mean 4092, +16 sigma)
#define GBLK 512                 // gather block threads

// ---------------- K1: bucket histogram (int4 loads, LDS-aggregated) ----------------
__global__ __launch_bounds__(256) void hist_kernel(const int* __restrict__ dst,
                                                   int* __restrict__ bucketCount,
                                                   int E4, int nbucket) {
    __shared__ int h[MAXBKT];
    for (int i = threadIdx.x; i < MAXBKT; i += 256) h[i] = 0;
    __syncthreads();
    const int4* dst4 = (const int4*)dst;
    int tbase4 = blockIdx.x * (TILE / 4);
    #pragma unroll
    for (int k = 0; k < PT / 4; k++) {
        int i4 = tbase4 + k * 256 + threadIdx.x;
        if (i4 < E4) {
            int4 d = dst4[i4];
            atomicAdd(&h[d.x >> BSHIFT], 1);
            atomicAdd(&h[d.y >> BSHIFT], 1);
            atomicAdd(&h[d.z >> BSHIFT], 1);
            atomicAdd(&h[d.w >> BSHIFT], 1);
        }
    }
    __syncthreads();
    for (int i = threadIdx.x; i < nbucket; i += 256) {
        int c = h[i];
        if (c) atomicAdd(&bucketCount[i], c);
    }
}

// ---------------- K2: scan bucket counts -> bases + cursors (2 bins/thread) ----------------
__global__ __launch_bounds__(256) void scan_kernel(const int* __restrict__ bucketCount,
                                                   int* __restrict__ bucketBase,
                                                   int* __restrict__ bucketCursor,
                                                   int nbucket, int E) {
    __shared__ int lds[256];
    int tid = threadIdx.x;
    int v0 = bucketCount[2 * tid];          // bins >= nbucket are zero (memset)
    int v1 = bucketCount[2 * tid + 1];
    int s = v0 + v1;
    lds[tid] = s;
    __syncthreads();
    for (int off = 1; off < 256; off <<= 1) {
        int t = (tid >= off) ? lds[tid - off] : 0;
        __syncthreads();
        lds[tid] += t;
        __syncthreads();
    }
    int run = lds[tid] - s;                 // exclusive prefix
    bucketBase[2 * tid] = run;       bucketCursor[2 * tid] = run;
    bucketBase[2 * tid + 1] = run + v0; bucketCursor[2 * tid + 1] = run + v0;
    if (tid == 255) bucketBase[512] = run + s;   // == E
}

// ---------------- K3: partition with LDS stage-reorder (coalesced key writes) ----------------
// key = (local_node << 21) | eid   (local<128, eid<2^21)
__global__ __launch_bounds__(256) void partition_kernel(const int* __restrict__ dst,
                                                        int* __restrict__ bucketCursor,
                                                        unsigned int* __restrict__ keys,
                                                        int E4, int nbucket) {
    __shared__ int h[MAXBKT];              // counts, then reused as stage cursor
    __shared__ int hoff[MAXBKT + 1];       // local exclusive offsets
    __shared__ int gbase[MAXBKT];          // claimed global bases
    __shared__ int scanb[256];
    __shared__ unsigned int stage[TILE];
    int tid = threadIdx.x;
    for (int i = tid; i < MAXBKT; i += 256) h[i] = 0;
    __syncthreads();
    const int4* dst4 = (const int4*)dst;
    int tbase4 = blockIdx.x * (TILE / 4);
    // pass 1: local bucket counts
    #pragma unroll
    for (int k = 0; k < PT / 4; k++) {
        int i4 = tbase4 + k * 256 + tid;
        if (i4 < E4) {
            int4 d = dst4[i4];
            atomicAdd(&h[d.x >> BSHIFT], 1);
            atomicAdd(&h[d.y >> BSHIFT], 1);
            atomicAdd(&h[d.z >> BSHIFT], 1);
            atomicAdd(&h[d.w >> BSHIFT], 1);
        }
    }
    __syncthreads();
    // local scan (2 bins per thread)
    int v0 = h[2 * tid], v1 = h[2 * tid + 1];
    int s = v0 + v1;
    scanb[tid] = s;
    __syncthreads();
    for (int off = 1; off < 256; off <<= 1) {
        int t = (tid >= off) ? scanb[tid - off] : 0;
        __syncthreads();
        scanb[tid] += t;
        __syncthreads();
    }
    int run = scanb[tid] - s;
    hoff[2 * tid] = run;
    hoff[2 * tid + 1] = run + v0;
    if (tid == 255) hoff[512] = run + s;
    // claim global cursor space per bucket
    for (int i = tid; i < nbucket; i += 256) {
        int c = h[i];
        gbase[i] = c ? atomicAdd(&bucketCursor[i], c) : 0;
    }
    __syncthreads();
    // reset h to local offsets (stage cursors)
    for (int i = tid; i < MAXBKT; i += 256) h[i] = hoff[i];
    __syncthreads();
    // pass 2: rank + scatter packed keys into LDS stage
    #pragma unroll
    for (int k = 0; k < PT / 4; k++) {
        int i4 = tbase4 + k * 256 + tid;
        if (i4 < E4) {
            int4 d = dst4[i4];
            int e = i4 * 4;
            int r;
            r = atomicAdd(&h[d.x >> BSHIFT], 1);
            stage[r] = ((unsigned)(d.x & (NODES_PER_BKT - 1)) << 21) | (unsigned)e;
            r = atomicAdd(&h[d.y >> BSHIFT], 1);
            stage[r] = ((unsigned)(d.y & (NODES_PER_BKT - 1)) << 21) | (unsigned)(e + 1);
            r = atomicAdd(&h[d.z >> BSHIFT], 1);
            stage[r] = ((unsigned)(d.z & (NODES_PER_BKT - 1)) << 21) | (unsigned)(e + 2);
            r = atomicAdd(&h[d.w >> BSHIFT], 1);
            stage[r] = ((unsigned)(d.w & (NODES_PER_BKT - 1)) << 21) | (unsigned)(e + 3);
        }
    }
    __syncthreads();
    // write out: per-bucket contiguous runs (L2 write-combines into full lines)
    for (int i = tid; i < nbucket; i += 256) {
        int lo = hoff[i], hi = hoff[i + 1];
        int g = gbase[i];
        for (int j = lo; j < hi; j++) keys[g + (j - lo)] = stage[j];
    }
}

// ---------------- K4: LDS counting-sort (128 bins) + float4 group gather ----------------
__global__ __launch_bounds__(GBLK) void bucket_gather_kernel(
        const float* __restrict__ m,
        const unsigned int* __restrict__ keys,
        const int* __restrict__ bucketBase,
        const float* __restrict__ w,
        const float* __restrict__ bia,
        float* __restrict__ out, int N) {
    __shared__ int seid[CAPG];
    __shared__ int nh[NODES_PER_BKT];
    __shared__ int noff[NODES_PER_BKT + 1];
    __shared__ int ncur[NODES_PER_BKT];
    int bkt = blockIdx.x;
    int tid = threadIdx.x;
    int start = bucketBase[bkt];
    int cnt = bucketBase[bkt + 1] - start;
    if (cnt > CAPG) cnt = CAPG;          // statistically impossible; OOB guard

    for (int i = tid; i < NODES_PER_BKT; i += GBLK) nh[i] = 0;
    __syncthreads();
    for (int i = tid; i < cnt; i += GBLK)
        atomicAdd(&nh[keys[start + i] >> 21], 1);
    __syncthreads();
    if (tid < 64) {                       // wave 0: scan 128 bins, 2 per lane
        int a0 = nh[2 * tid], a1 = nh[2 * tid + 1];
        int s = a0 + a1;
        int x = s;
        #pragma unroll
        for (int off = 1; off < 64; off <<= 1) {
            int t = __shfl_up(x, off, 64);
            if (tid >= off) x += t;
        }
        int base = x - s;                 // exclusive
        noff[2 * tid] = base;      ncur[2 * tid] = base;
        noff[2 * tid + 1] = base + a0; ncur[2 * tid + 1] = base + a0;
        if (tid == 63) noff[NODES_PER_BKT] = x;
    }
    __syncthreads();
    for (int i = tid; i < cnt; i += GBLK) {
        unsigned int k = keys[start + i];   // L2-warm second read
        int pos = atomicAdd(&ncur[k >> 21], 1);
        seid[pos] = (int)(k & 0x1FFFFFu);
    }
    __syncthreads();

    // gather: 8-lane group per node; fo = float4 feature chunk; 8 rows per wave load
    const int fo  = tid & 7;
    const int grp = tid >> 3;             // 0..63
    const float w0 = w[0], w1 = w[1], w2 = w[2], w3 = w[3], bb = bia[0];

    for (int nl = grp; nl < NODES_PER_BKT; nl += 64) {
        int node = (bkt << BSHIFT) + nl;
        if (node >= N) break;
        int s0 = noff[nl];     if (s0 > cnt) s0 = cnt;
        int e0 = noff[nl + 1]; if (e0 > cnt) e0 = cnt;
        int deg = e0 - s0;
        float sa0 = 0.f, sa1 = 0.f, sa2 = 0.f, sa3 = 0.f;
        float mn0 = INFINITY, mn1 = INFINITY, mn2 = INFINITY, mn3 = INFINITY;
        float mx0 = -INFINITY, mx1 = -INFINITY, mx2 = -INFINITY, mx3 = -INFINITY;

#define ACC(v)                                                      \
        sa0 += (v).x; mn0 = fminf(mn0, (v).x); mx0 = fmaxf(mx0, (v).x); \
        sa1 += (v).y; mn1 = fminf(mn1, (v).y); mx1 = fmaxf(mx1, (v).y); \
        sa2 += (v).z; mn2 = fminf(mn2, (v).z); mx2 = fmaxf(mx2, (v).z); \
        sa3 += (v).w; mn3 = fminf(mn3, (v).w); mx3 = fmaxf(mx3, (v).w);

        int j = s0;
        for (; j + 4 <= e0; j += 4) {
            int ea = seid[j], eb = seid[j + 1], ec = seid[j + 2], ed = seid[j + 3];
            float4 va = *(const float4*)&m[ea * D_FEAT + (fo << 2)];
            float4 vb = *(const float4*)&m[eb * D_FEAT + (fo << 2)];
            float4 vc = *(const float4*)&m[ec * D_FEAT + (fo << 2)];
            float4 vd = *(const float4*)&m[ed * D_FEAT + (fo << 2)];
            ACC(va); ACC(vb); ACC(vc); ACC(vd);
        }
        for (; j < e0; j++) {
            float4 v = *(const float4*)&m[seid[j] * D_FEAT + (fo << 2)];
            ACC(v);
        }
#undef ACC

        bool has = deg > 0;
        float inv = 1.0f / fmaxf((float)deg, 1.0f);
        float4 o;
        o.x = w0 * sa0 + w1 * (has ? mn0 : 0.f) + w2 * (has ? mx0 : 0.f) + w3 * (sa0 * inv) + bb;
        o.y = w0 * sa1 + w1 * (has ? mn1 : 0.f) + w2 * (has ? mx1 : 0.f) + w3 * (sa1 * inv) + bb;
        o.z = w0 * sa2 + w1 * (has ? mn2 : 0.f) + w2 * (has ? mx2 : 0.f) + w3 * (sa2 * inv) + bb;
        o.w = w0 * sa3 + w1 * (has ? mn3 : 0.f) + w2 * (has ? mx3 : 0.f) + w3 * (sa3 * inv) + bb;
        *(float4*)&out[node * D_FEAT + (fo << 2)] = o;
    }
}

extern "C" void kernel_launch(void* const* d_in, const int* in_sizes, int n_in,
                              void* d_out, int out_size, void* d_ws, size_t ws_size,
                              hipStream_t stream) {
    const float* m   = (const float*)d_in[0];
    const int*   dst = (const int*)  d_in[1];
    const float* w   = (const float*)d_in[2];
    const float* b   = (const float*)d_in[3];

    int E = in_sizes[0] / D_FEAT;           // 1,600,000 (divisible by 4)
    int N = out_size    / D_FEAT;           // 50,000
    int E4 = E / 4;
    int nbucket = (N + NODES_PER_BKT - 1) >> BSHIFT;   // 391

    int* ws           = (int*)d_ws;
    int* bucketCount  = ws;                             // MAXBKT
    int* bucketBase   = bucketCount + MAXBKT;           // MAXBKT+1
    int* bucketCursor = bucketBase + MAXBKT + 1;        // MAXBKT
    unsigned int* keys = (unsigned int*)(bucketCursor + MAXBKT);   // E

    int nTiles = (E + TILE - 1) / TILE;     // 196

    hipMemsetAsync(bucketCount, 0, MAXBKT * sizeof(int), stream);
    hipLaunchKernelGGL(hist_kernel, dim3(nTiles), dim3(256), 0, stream,
                       dst, bucketCount, E4, nbucket);
    hipLaunchKernelGGL(scan_kernel, dim3(1), dim3(256), 0, stream,
                       bucketCount, bucketBase, bucketCursor, nbucket, E);
    hipLaunchKernelGGL(partition_kernel, dim3(nTiles), dim3(256), 0, stream,
                       dst, bucketCursor, keys, E4, nbucket);
    hipLaunchKernelGGL(bucket_gather_kernel, dim3(nbucket), dim3(GBLK), 0, stream,
                       m, keys, bucketBase, w, b, (float*)d_out, N);
}